// Round 2
// baseline (601.652 us; speedup 1.0000x reference)
//
#include <hip/hip_runtime.h>
#include <cstdint>
#include <cstddef>

#define NBATCH 128
#define NCH    256
#define NHW    1024
#define NTIME  64
#define NCLS   128

typedef _Float16 half2_t __attribute__((ext_vector_type(2)));

#if defined(__has_builtin)
#  if __has_builtin(__builtin_amdgcn_fdot2)
#    define HAS_FDOT2 1
#  endif
#endif
#ifndef HAS_FDOT2
#  define HAS_FDOT2 0
#endif

__device__ __forceinline__ float dot2acc(half2_t a, half2_t b, float c){
#if HAS_FDOT2
  return __builtin_amdgcn_fdot2(a, b, c, false);
#else
  return c + (float)a.x*(float)b.x + (float)a.y*(float)b.y;
#endif
}

__device__ __forceinline__ half2_t pack2(float x, float y){
  half2_t p; p.x = (_Float16)x; p.y = (_Float16)y; return p;
}

__device__ __forceinline__ float sig_(float x){
  x = fminf(30.f, fmaxf(-30.f, x));
  return 1.f/(1.f+__expf(-x));
}
__device__ __forceinline__ float tanh_(float x){
  x = fminf(15.f, fmaxf(-15.f, x));
  float e = __expf(2.f*x);
  return (e-1.f)/(e+1.f);
}

// ---------------- K0: row sums of A -> S[b*64+t] ----------------
__global__ __launch_bounds__(256) void k_rowsum(const float* __restrict__ A, float* __restrict__ S){
  int row = blockIdx.x;                       // b*64+t
  const float4* a4 = (const float4*)(A + (size_t)row*NHW);
  float4 v = a4[threadIdx.x];
  float s = v.x+v.y+v.z+v.w;
  #pragma unroll
  for (int off=32; off>0; off>>=1) s += __shfl_down(s, off, 64);
  __shared__ float wsum[4];
  int lane = threadIdx.x & 63, w = threadIdx.x >> 6;
  if (lane==0) wsum[w] = s;
  __syncthreads();
  if (threadIdx.x==0) S[row] = wsum[0]+wsum[1]+wsum[2]+wsum[3];
}

// ---------------- K1: attention pooling  C[t][b][c] = sum_hw feat[b][c][hw]*A[b][t][hw]/S ---
__global__ __launch_bounds__(256) void k_pool(const float* __restrict__ feat, const float* __restrict__ A,
                                              const float* __restrict__ S, float* __restrict__ C){
  __shared__ float As[64*65];
  __shared__ float Fs[64*65];
  __shared__ float sinv[64];
  int b = blockIdx.x, c0 = blockIdx.y*64, tid = threadIdx.x;
  if (tid < 64) sinv[tid] = 1.f / S[b*64 + tid];
  float acc[4][4] = {};
  int rq = tid>>4, cq = tid&15;
  for (int k0=0;k0<NHW;k0+=64){
    __syncthreads();
    #pragma unroll
    for (int j=0;j<4;j++){
      int f4 = j*256+tid, r = f4>>4, cc = (f4&15)*4;
      float4 va = *(const float4*)(A + ((size_t)(b*64+r))*NHW + k0 + cc);
      As[r*65+cc+0]=va.x; As[r*65+cc+1]=va.y; As[r*65+cc+2]=va.z; As[r*65+cc+3]=va.w;
      float4 vf = *(const float4*)(feat + ((size_t)(b*256+c0+r))*NHW + k0 + cc);
      Fs[r*65+cc+0]=vf.x; Fs[r*65+cc+1]=vf.y; Fs[r*65+cc+2]=vf.z; Fs[r*65+cc+3]=vf.w;
    }
    __syncthreads();
    #pragma unroll 8
    for (int k=0;k<64;k++){
      float xa[4], wb[4];
      #pragma unroll
      for (int i=0;i<4;i++) xa[i] = As[(rq*4+i)*65+k];
      #pragma unroll
      for (int j=0;j<4;j++) wb[j] = Fs[(cq*4+j)*65+k];
      #pragma unroll
      for (int i=0;i<4;i++)
        #pragma unroll
        for (int j=0;j<4;j++) acc[i][j] += xa[i]*wb[j];
    }
  }
  #pragma unroll
  for (int i=0;i<4;i++){
    int t = rq*4+i;
    float is = sinv[t];
    float4 o; o.x=acc[i][0]*is; o.y=acc[i][1]*is; o.z=acc[i][2]*is; o.w=acc[i][3]*is;
    *(float4*)(C + ((size_t)t*NBATCH + b)*NCH + c0 + cq*4) = o;
  }
}

// ---------------- generic GEMM: out[M][N] = X[M][K] @ W[N][K]^T + ba + bb ----------------
__global__ __launch_bounds__(256) void k_gemm_bias(const float* __restrict__ X, const float* __restrict__ W,
    const float* __restrict__ ba, const float* __restrict__ bb, float* __restrict__ out, int N, int K){
  __shared__ float Xs[64*65];
  __shared__ float Ws[64*65];
  int m0 = blockIdx.y*64, n0 = blockIdx.x*64, tid = threadIdx.x;
  float acc[4][4] = {};
  int rq = tid>>4, cq = tid&15;
  for (int k0=0;k0<K;k0+=64){
    __syncthreads();
    #pragma unroll
    for (int j=0;j<4;j++){
      int f4 = j*256+tid, r = f4>>4, cc = (f4&15)*4;
      float4 vx = *(const float4*)(X + (size_t)(m0+r)*K + k0 + cc);
      Xs[r*65+cc+0]=vx.x; Xs[r*65+cc+1]=vx.y; Xs[r*65+cc+2]=vx.z; Xs[r*65+cc+3]=vx.w;
      float4 vw = *(const float4*)(W + (size_t)(n0+r)*K + k0 + cc);
      Ws[r*65+cc+0]=vw.x; Ws[r*65+cc+1]=vw.y; Ws[r*65+cc+2]=vw.z; Ws[r*65+cc+3]=vw.w;
    }
    __syncthreads();
    #pragma unroll 8
    for (int k=0;k<64;k++){
      float xa[4], wb[4];
      #pragma unroll
      for (int i=0;i<4;i++) xa[i] = Xs[(rq*4+i)*65+k];
      #pragma unroll
      for (int j=0;j<4;j++) wb[j] = Ws[(cq*4+j)*65+k];
      #pragma unroll
      for (int i=0;i<4;i++)
        #pragma unroll
        for (int j=0;j<4;j++) acc[i][j] += xa[i]*wb[j];
    }
  }
  float bs[4];
  #pragma unroll
  for (int j=0;j<4;j++){ int n = n0+cq*4+j; bs[j] = ba[n] + (bb ? bb[n] : 0.f); }
  #pragma unroll
  for (int i=0;i<4;i++){
    float4 o; o.x=acc[i][0]+bs[0]; o.y=acc[i][1]+bs[1]; o.z=acc[i][2]+bs[2]; o.w=acc[i][3]+bs[3];
    *(float4*)(out + (size_t)(m0+rq*4+i)*N + n0 + cq*4) = o;
  }
}

// ---------------- K7: packed normalized attention output ----------------
__global__ __launch_bounds__(256) void k_attns(const float* __restrict__ A, const float* __restrict__ S,
    const int* __restrict__ pack_b, const int* __restrict__ pack_t, float* __restrict__ outA){
  int i = blockIdx.x;
  int b = pack_b[i], t = pack_t[i];
  float is = 1.f / S[b*64 + t];
  float4 v = ((const float4*)(A + ((size_t)(b*64+t))*NHW))[threadIdx.x];
  v.x*=is; v.y*=is; v.z*=is; v.w*=is;
  ((float4*)(outA + (size_t)i*NHW))[threadIdx.x] = v;
}

// ---------------- K3: BiLSTM scan, readlane broadcast, f16 weights in regs ----------------
// 256 blocks = 128 samples x 2 dirs, 512 threads = 512 gate rows.
__global__ __launch_bounds__(512, 2) void k_lstm(const float* __restrict__ Gf, const float* __restrict__ Gb,
    const float* __restrict__ Whh_f, const float* __restrict__ Whh_b, float* __restrict__ Cl){
  int b = blockIdx.x & 127, dir = blockIdx.x >> 7;
  int g = threadIdx.x, lane = g & 63;
  const float* Whh = dir ? Whh_b : Whh_f;
  const float* G   = dir ? Gb    : Gf;
  // weights: row g, 128 cols -> 64 half2 VGPRs
  half2_t wp[64];
  {
    const float4* wr = (const float4*)(Whh + (size_t)g*128);
    #pragma unroll
    for (int j=0;j<32;j++){
      float4 v = wr[j];
      wp[2*j]   = pack2(v.x, v.y);
      wp[2*j+1] = pack2(v.z, v.w);
    }
  }
  __shared__ float h32[128];
  __shared__ float gates[512];
  if (g < 128) h32[g] = 0.f;
  float c = 0.f;
  __syncthreads();
  #pragma unroll 1
  for (int t=0;t<NTIME;t++){
    int tt = dir ? (NTIME-1-t) : t;
    // prefetch gate-input (bias already folded in by k_gemm_bias)
    float gv = G[((size_t)tt*NBATCH + b)*512 + g];
    // each lane picks up h pair (2 fp32 -> half2); lane l owns h[2l],h[2l+1]
    float2 hp2 = *(const float2*)(h32 + 2*lane);
    int hpk = __builtin_bit_cast(int, pack2(hp2.x, hp2.y));
    float acc[4] = {0.f,0.f,0.f,0.f};
    #pragma unroll
    for (int p=0;p<64;p++){
      int hv = __builtin_amdgcn_readlane(hpk, p);
      acc[p&3] = dot2acc(wp[p], __builtin_bit_cast(half2_t, hv), acc[p&3]);
    }
    gates[g] = gv + acc[0]+acc[1]+acc[2]+acc[3];
    __syncthreads();
    if (g < 128){
      float gi=gates[g], gf=gates[128+g], gg=gates[256+g], go=gates[384+g];
      c = sig_(gf)*c + sig_(gi)*tanh_(gg);
      float h = sig_(go)*tanh_(c);
      h32[g] = h;
      Cl[((size_t)tt*NBATCH + b)*NCH + dir*128 + g] = h;
    }
    __syncthreads();
  }
}

// ---------------- K4a: xs = [Cl, prev_emb] ----------------
__global__ __launch_bounds__(256) void k_xs(const float* __restrict__ Cl, const float* __restrict__ emb,
    const int* __restrict__ text, float* __restrict__ xs){
  int idx = blockIdx.x*256 + threadIdx.x;     // float4 index, 1,048,576 total
  int row = idx>>7, c4 = idx&127;             // row = t*128+b, 128 float4 per row
  int t = row>>7, b = row&127;
  float4 v;
  if (c4 < 64) v = ((const float4*)Cl)[(size_t)row*64 + c4];
  else {
    int cls = (t==0) ? 0 : text[b*64 + (t-1)];
    v = ((const float4*)emb)[(size_t)cls*64 + (c4-64)];
  }
  ((float4*)xs)[(size_t)row*128 + c4] = v;
}

// ---------------- K5: GRU scan, readlane broadcast, f16 weights in regs ----------------
// 128 blocks = samples, 768 threads = 768 gate rows (r,z,n x 256).
__global__ __launch_bounds__(768, 3) void k_gru(const float* __restrict__ gx, const float* __restrict__ Whh_g,
    const float* __restrict__ bhh_g, float* __restrict__ hs){
  int b = blockIdx.x, g = threadIdx.x, lane = g & 63;
  // weights: row g, 256 cols -> 128 half2 VGPRs
  half2_t wp[128];
  {
    const float4* wr = (const float4*)(Whh_g + (size_t)g*256);
    #pragma unroll
    for (int j=0;j<64;j++){
      float4 v = wr[j];
      wp[2*j]   = pack2(v.x, v.y);
      wp[2*j+1] = pack2(v.z, v.w);
    }
  }
  float bh = bhh_g[g];
  __shared__ float h32[256];
  __shared__ float ghs[768];
  if (g < 256) h32[g] = 0.f;
  float hprev = 0.f;
  __syncthreads();
  #pragma unroll 1
  for (int t=0;t<NTIME;t++){
    // prefetch gate inputs for this timestep (used after the matvec)
    float gr=0.f, gz=0.f, gn=0.f;
    if (g < 256){
      const float* gxp = gx + ((size_t)t*NBATCH + b)*768;
      gr = gxp[g]; gz = gxp[256+g]; gn = gxp[512+g];
    }
    // each lane picks up its 4 h values (lane l owns h[4l..4l+3]) -> 2 half2
    float4 hq = *(const float4*)(h32 + 4*lane);
    int hpk0 = __builtin_bit_cast(int, pack2(hq.x, hq.y));
    int hpk1 = __builtin_bit_cast(int, pack2(hq.z, hq.w));
    float acc[4] = {0.f,0.f,0.f,0.f};
    #pragma unroll
    for (int p=0;p<128;p++){
      int hv = __builtin_amdgcn_readlane((p&1) ? hpk1 : hpk0, p>>1);
      acc[p&3] = dot2acc(wp[p], __builtin_bit_cast(half2_t, hv), acc[p&3]);
    }
    ghs[g] = bh + acc[0]+acc[1]+acc[2]+acc[3];
    __syncthreads();
    if (g < 256){
      float r = sig_(gr + ghs[g]);
      float z = sig_(gz + ghs[256+g]);
      float n = tanh_(gn + r*ghs[512+g]);
      float h = (1.f-z)*n + z*hprev;
      hprev = h;
      h32[g] = h;
      hs[((size_t)t*NBATCH + b)*NCH + g] = h;
    }
    __syncthreads();
  }
}

// ---------------- K6: logits for packed rows (gather + GEMM + bias) ----------------
__global__ __launch_bounds__(256) void k_logits(const float* __restrict__ hs, const int* __restrict__ pack_t,
    const int* __restrict__ pack_b, const float* __restrict__ W, const float* __restrict__ bias,
    float* __restrict__ out, int L){
  __shared__ float Xs[64*65];
  __shared__ float Ws[64*65];
  __shared__ int rt[64], rb[64];
  int m0 = blockIdx.y*64, n0 = blockIdx.x*64, tid = threadIdx.x;
  if (tid < 64){
    int m = m0 + tid;
    rt[tid] = (m<L) ? pack_t[m] : 0;
    rb[tid] = (m<L) ? pack_b[m] : 0;
  }
  float acc[4][4] = {};
  int rq = tid>>4, cq = tid&15;
  __syncthreads();
  for (int k0=0;k0<256;k0+=64){
    __syncthreads();
    #pragma unroll
    for (int j=0;j<4;j++){
      int f4 = j*256+tid, r = f4>>4, cc = (f4&15)*4;
      float4 vx = *(const float4*)(hs + ((size_t)rt[r]*NBATCH + rb[r])*NCH + k0 + cc);
      Xs[r*65+cc+0]=vx.x; Xs[r*65+cc+1]=vx.y; Xs[r*65+cc+2]=vx.z; Xs[r*65+cc+3]=vx.w;
      float4 vw = *(const float4*)(W + (size_t)(n0+r)*256 + k0 + cc);
      Ws[r*65+cc+0]=vw.x; Ws[r*65+cc+1]=vw.y; Ws[r*65+cc+2]=vw.z; Ws[r*65+cc+3]=vw.w;
    }
    __syncthreads();
    #pragma unroll 8
    for (int k=0;k<64;k++){
      float xa[4], wb[4];
      #pragma unroll
      for (int i=0;i<4;i++) xa[i] = Xs[(rq*4+i)*65+k];
      #pragma unroll
      for (int j=0;j<4;j++) wb[j] = Ws[(cq*4+j)*65+k];
      #pragma unroll
      for (int i=0;i<4;i++)
        #pragma unroll
        for (int j=0;j<4;j++) acc[i][j] += xa[i]*wb[j];
    }
  }
  float bs[4];
  #pragma unroll
  for (int j=0;j<4;j++) bs[j] = bias[n0+cq*4+j];
  #pragma unroll
  for (int i=0;i<4;i++){
    int m = m0 + rq*4 + i;
    if (m < L){
      float4 o; o.x=acc[i][0]+bs[0]; o.y=acc[i][1]+bs[1]; o.z=acc[i][2]+bs[2]; o.w=acc[i][3]+bs[3];
      *(float4*)(out + (size_t)m*NCLS + n0 + cq*4) = o;
    }
  }
}

extern "C" void kernel_launch(void* const* d_in, const int* in_sizes, int n_in,
                              void* d_out, int out_size, void* d_ws, size_t ws_size,
                              hipStream_t stream) {
  const float* feature = (const float*)d_in[0];
  const float* A       = (const float*)d_in[1];
  const int*   text    = (const int*)d_in[2];
  const int*   pack_b  = (const int*)d_in[4];
  const int*   pack_t  = (const int*)d_in[5];
  const float* emb     = (const float*)d_in[6];
  const float* Wih_f   = (const float*)d_in[7];
  const float* Whh_f   = (const float*)d_in[8];
  const float* bih_f   = (const float*)d_in[9];
  const float* bhh_f   = (const float*)d_in[10];
  const float* Wih_b   = (const float*)d_in[11];
  const float* Whh_b   = (const float*)d_in[12];
  const float* bih_b   = (const float*)d_in[13];
  const float* bhh_b   = (const float*)d_in[14];
  const float* Wih_g   = (const float*)d_in[15];
  const float* Whh_g   = (const float*)d_in[16];
  const float* bih_g   = (const float*)d_in[17];
  const float* bhh_g   = (const float*)d_in[18];
  const float* Wgen    = (const float*)d_in[19];
  const float* bgen    = (const float*)d_in[20];
  int L = in_sizes[4];

  char* ws = (char*)d_ws;
  const size_t MB = 1u<<20;
  float* S   = (float*)(ws + 0);
  float* C   = (float*)(ws + 1*MB);    // 8 MB  [t][b][256]
  float* Cl  = (float*)(ws + 9*MB);    // 8 MB  [t][b][256]
  float* hs  = (float*)(ws + 17*MB);   // 8 MB  [t][b][256]
  float* Gf  = (float*)(ws + 25*MB);   // 16 MB [t][b][512]  (dead after k_lstm)
  float* Gb  = (float*)(ws + 41*MB);   // 16 MB [t][b][512]  (dead after k_lstm)
  float* xs  = (float*)(ws + 25*MB);   // 16 MB, aliases Gf (written after k_lstm)
  float* gx  = (float*)(ws + 41*MB);   // 24 MB, aliases Gb (written after k_lstm)

  float* out_res   = (float*)d_out;
  float* out_attns = out_res + (size_t)L*NCLS;

  k_rowsum<<<8192, 256, 0, stream>>>(A, S);
  k_pool<<<dim3(128,4), 256, 0, stream>>>(feature, A, S, C);
  k_attns<<<L, 256, 0, stream>>>(A, S, pack_b, pack_t, out_attns);
  k_gemm_bias<<<dim3(8,128), 256, 0, stream>>>(C, Wih_f, bih_f, bhh_f, Gf, 512, 256);
  k_gemm_bias<<<dim3(8,128), 256, 0, stream>>>(C, Wih_b, bih_b, bhh_b, Gb, 512, 256);
  k_lstm<<<256, 512, 0, stream>>>(Gf, Gb, Whh_f, Whh_b, Cl);
  k_xs<<<4096, 256, 0, stream>>>(Cl, emb, text, xs);
  k_gemm_bias<<<dim3(12,128), 256, 0, stream>>>(xs, Wih_g, bih_g, nullptr, gx, 768, 512);
  k_gru<<<128, 768, 0, stream>>>(gx, Whh_g, bhh_g, hs);
  k_logits<<<dim3(2,(L+63)/64), 256, 0, stream>>>(hs, pack_t, pack_b, Wgen, bgen, out_res, L);
}

// Round 6
// 557.966 us; speedup vs baseline: 1.0783x; 1.0783x over previous
//
#include <hip/hip_runtime.h>
#include <cstdint>
#include <cstddef>

#define NBATCH 128
#define NCH    256
#define NHW    1024
#define NTIME  64
#define NCLS   128

typedef _Float16 half2_t __attribute__((ext_vector_type(2)));

#if defined(__has_builtin)
#  if __has_builtin(__builtin_amdgcn_fdot2)
#    define HAS_FDOT2 1
#  endif
#endif
#ifndef HAS_FDOT2
#  define HAS_FDOT2 0
#endif

__device__ __forceinline__ float dot2acc(half2_t a, half2_t b, float c){
#if HAS_FDOT2
  return __builtin_amdgcn_fdot2(a, b, c, false);
#else
  return c + (float)a.x*(float)b.x + (float)a.y*(float)b.y;
#endif
}
__device__ __forceinline__ half2_t pack2(float x, float y){
  half2_t p; p.x = (_Float16)x; p.y = (_Float16)y; return p;
}
__device__ __forceinline__ float sig_(float x){
  x = fminf(30.f, fmaxf(-30.f, x));
  return 1.f/(1.f+__expf(-x));
}
__device__ __forceinline__ float tanh_(float x){
  x = fminf(15.f, fmaxf(-15.f, x));
  float e = __expf(2.f*x);
  return (e-1.f)/(e+1.f);
}

// ---------------- K0: row sums of A -> S[b*64+t] ----------------
__global__ __launch_bounds__(256) void k_rowsum(const float* __restrict__ A, float* __restrict__ S){
  int row = blockIdx.x;                       // b*64+t
  const float4* a4 = (const float4*)(A + (size_t)row*NHW);
  float4 v = a4[threadIdx.x];
  float s = v.x+v.y+v.z+v.w;
  #pragma unroll
  for (int off=32; off>0; off>>=1) s += __shfl_down(s, off, 64);
  __shared__ float wsum[4];
  int lane = threadIdx.x & 63, w = threadIdx.x >> 6;
  if (lane==0) wsum[w] = s;
  __syncthreads();
  if (threadIdx.x==0) S[row] = wsum[0]+wsum[1]+wsum[2]+wsum[3];
}

// ---------------- K1: attention pooling (fp32 SIMT, known-good) ----------------
__global__ __launch_bounds__(256) void k_pool(const float* __restrict__ feat, const float* __restrict__ A,
                                              const float* __restrict__ S, float* __restrict__ C){
  __shared__ float As[64*65];
  __shared__ float Fs[64*65];
  __shared__ float sinv[64];
  int b = blockIdx.x, c0 = blockIdx.y*64, tid = threadIdx.x;
  if (tid < 64) sinv[tid] = 1.f / S[b*64 + tid];
  float acc[4][4] = {};
  int rq = tid>>4, cq = tid&15;
  for (int k0=0;k0<NHW;k0+=64){
    __syncthreads();
    #pragma unroll
    for (int j=0;j<4;j++){
      int f4 = j*256+tid, r = f4>>4, cc = (f4&15)*4;
      float4 va = *(const float4*)(A + ((size_t)(b*64+r))*NHW + k0 + cc);
      As[r*65+cc+0]=va.x; As[r*65+cc+1]=va.y; As[r*65+cc+2]=va.z; As[r*65+cc+3]=va.w;
      float4 vf = *(const float4*)(feat + ((size_t)(b*256+c0+r))*NHW + k0 + cc);
      Fs[r*65+cc+0]=vf.x; Fs[r*65+cc+1]=vf.y; Fs[r*65+cc+2]=vf.z; Fs[r*65+cc+3]=vf.w;
    }
    __syncthreads();
    #pragma unroll 8
    for (int k=0;k<64;k++){
      float xa[4], wb[4];
      #pragma unroll
      for (int i=0;i<4;i++) xa[i] = As[(rq*4+i)*65+k];
      #pragma unroll
      for (int j=0;j<4;j++) wb[j] = Fs[(cq*4+j)*65+k];
      #pragma unroll
      for (int i=0;i<4;i++)
        #pragma unroll
        for (int j=0;j<4;j++) acc[i][j] += xa[i]*wb[j];
    }
  }
  #pragma unroll
  for (int i=0;i<4;i++){
    int t = rq*4+i;
    float is = sinv[t];
    float4 o; o.x=acc[i][0]*is; o.y=acc[i][1]*is; o.z=acc[i][2]*is; o.w=acc[i][3]*is;
    *(float4*)(C + ((size_t)t*NBATCH + b)*NCH + c0 + cq*4) = o;
  }
}

// ---------------- generic GEMM (fp32 SIMT, known-good): out = X@W^T + ba(+bb) ----------------
__global__ __launch_bounds__(256) void k_gemm_bias(const float* __restrict__ X, const float* __restrict__ W,
    const float* __restrict__ ba, const float* __restrict__ bb, float* __restrict__ out, int N, int K){
  __shared__ float Xs[64*65];
  __shared__ float Ws[64*65];
  int m0 = blockIdx.y*64, n0 = blockIdx.x*64, tid = threadIdx.x;
  float acc[4][4] = {};
  int rq = tid>>4, cq = tid&15;
  for (int k0=0;k0<K;k0+=64){
    __syncthreads();
    #pragma unroll
    for (int j=0;j<4;j++){
      int f4 = j*256+tid, r = f4>>4, cc = (f4&15)*4;
      float4 vx = *(const float4*)(X + (size_t)(m0+r)*K + k0 + cc);
      Xs[r*65+cc+0]=vx.x; Xs[r*65+cc+1]=vx.y; Xs[r*65+cc+2]=vx.z; Xs[r*65+cc+3]=vx.w;
      float4 vw = *(const float4*)(W + (size_t)(n0+r)*K + k0 + cc);
      Ws[r*65+cc+0]=vw.x; Ws[r*65+cc+1]=vw.y; Ws[r*65+cc+2]=vw.z; Ws[r*65+cc+3]=vw.w;
    }
    __syncthreads();
    #pragma unroll 8
    for (int k=0;k<64;k++){
      float xa[4], wb[4];
      #pragma unroll
      for (int i=0;i<4;i++) xa[i] = Xs[(rq*4+i)*65+k];
      #pragma unroll
      for (int j=0;j<4;j++) wb[j] = Ws[(cq*4+j)*65+k];
      #pragma unroll
      for (int i=0;i<4;i++)
        #pragma unroll
        for (int j=0;j<4;j++) acc[i][j] += xa[i]*wb[j];
    }
  }
  float bs[4];
  #pragma unroll
  for (int j=0;j<4;j++){ int n = n0+cq*4+j; bs[j] = ba[n] + (bb ? bb[n] : 0.f); }
  #pragma unroll
  for (int i=0;i<4;i++){
    float4 o; o.x=acc[i][0]+bs[0]; o.y=acc[i][1]+bs[1]; o.z=acc[i][2]+bs[2]; o.w=acc[i][3]+bs[3];
    *(float4*)(out + (size_t)(m0+rq*4+i)*N + n0 + cq*4) = o;
  }
}

// ---------------- K7: packed normalized attention output ----------------
__global__ __launch_bounds__(256) void k_attns(const float* __restrict__ A, const float* __restrict__ S,
    const int* __restrict__ pack_b, const int* __restrict__ pack_t, float* __restrict__ outA){
  int i = blockIdx.x;
  int b = pack_b[i], t = pack_t[i];
  float is = 1.f / S[b*64 + t];
  float4 v = ((const float4*)(A + ((size_t)(b*64+t))*NHW))[threadIdx.x];
  v.x*=is; v.y*=is; v.z*=is; v.w*=is;
  ((float4*)(outA + (size_t)i*NHW))[threadIdx.x] = v;
}

// ---------------- K3: BiLSTM scan (R1-proposal version, PASSED) ----------------
// 256 blocks = 128 samples x 2 dirs, 512 threads = 512 gate rows.
__global__ __launch_bounds__(512, 2) void k_lstm(const float* __restrict__ Gf, const float* __restrict__ Gb,
    const float* __restrict__ Whh_f, const float* __restrict__ Whh_b, float* __restrict__ Cl){
  int b = blockIdx.x & 127, dir = blockIdx.x >> 7;
  int g = threadIdx.x, lane = g & 63;
  const float* Whh = dir ? Whh_b : Whh_f;
  const float* G   = dir ? Gb    : Gf;
  // weights: row g, 128 cols -> 64 half2 VGPRs
  half2_t wp[64];
  {
    const float4* wr = (const float4*)(Whh + (size_t)g*128);
    #pragma unroll
    for (int j=0;j<32;j++){
      float4 v = wr[j];
      wp[2*j]   = pack2(v.x, v.y);
      wp[2*j+1] = pack2(v.z, v.w);
    }
  }
  __shared__ float h32[128];
  __shared__ float gates[512];
  if (g < 128) h32[g] = 0.f;
  float c = 0.f;
  __syncthreads();
  #pragma unroll 1
  for (int t=0;t<NTIME;t++){
    int tt = dir ? (NTIME-1-t) : t;
    float gv = G[((size_t)tt*NBATCH + b)*512 + g];
    // lane l owns h[2l],h[2l+1] packed
    float2 hp2 = *(const float2*)(h32 + 2*lane);
    int hpk = __builtin_bit_cast(int, pack2(hp2.x, hp2.y));
    float acc[4] = {0.f,0.f,0.f,0.f};
    #pragma unroll
    for (int p=0;p<64;p++){
      int hv = __builtin_amdgcn_readlane(hpk, p);
      acc[p&3] = dot2acc(wp[p], __builtin_bit_cast(half2_t, hv), acc[p&3]);
    }
    gates[g] = gv + acc[0]+acc[1]+acc[2]+acc[3];
    __syncthreads();
    if (g < 128){
      float gi=gates[g], gf=gates[128+g], gg=gates[256+g], go=gates[384+g];
      c = sig_(gf)*c + sig_(gi)*tanh_(gg);
      float h = sig_(go)*tanh_(c);
      h32[g] = h;
      Cl[((size_t)tt*NBATCH + b)*NCH + dir*128 + g] = h;
    }
    __syncthreads();
  }
}

// ---------------- K4a: xs = [Cl, prev_emb] (fp32) ----------------
__global__ __launch_bounds__(256) void k_xs(const float* __restrict__ Cl, const float* __restrict__ emb,
    const int* __restrict__ text, float* __restrict__ xs){
  int idx = blockIdx.x*256 + threadIdx.x;     // float4 index, 1,048,576 total
  int row = idx>>7, c4 = idx&127;             // row = t*128+b
  int t = row>>7, b = row&127;
  float4 v;
  if (c4 < 64) v = ((const float4*)Cl)[(size_t)row*64 + c4];
  else {
    int cls = (t==0) ? 0 : text[b*64 + (t-1)];
    v = ((const float4*)emb)[(size_t)cls*64 + (c4-64)];
  }
  ((float4*)xs)[(size_t)row*128 + c4] = v;
}

// ---------------- K5: GRU scan, 512 threads, 3 half-row tasks/thread ----------------
// 1536 tasks = 768 rows x 2 k-halves. Chunk c = wave*3+s covers rows (c%12)*64+lane,
// k-half c/12 (wave-uniform -> readlane stays SGPR-indexed). 96 weight VGPRs/thread.
__global__ __launch_bounds__(512, 2) void k_gru(const float* __restrict__ gx,
    const float* __restrict__ Whh_g, const float* __restrict__ bhh_g, float* __restrict__ hs){
  int b = blockIdx.x, t0 = threadIdx.x, lane = t0 & 63, w = t0 >> 6;
  half2_t wp[3][64];
  int pidx[3];   // partLds index = hf*768 + row
  int hfb[3];    // readlane base = hf*32 (SGPR)
  #pragma unroll
  for (int s=0;s<3;s++){
    int c = w*3 + s;                 // 0..23
    int hf = (c >= 12) ? 1 : 0;
    int row = (c - hf*12)*64 + lane; // 0..767
    pidx[s] = hf*768 + row;
    hfb[s]  = __builtin_amdgcn_readfirstlane(hf*32);
    const float4* wr = (const float4*)(Whh_g + (size_t)row*256 + hf*128);
    #pragma unroll
    for (int j=0;j<32;j++){
      float4 v = wr[j];
      wp[s][2*j]   = pack2(v.x, v.y);
      wp[s][2*j+1] = pack2(v.z, v.w);
    }
  }
  __shared__ float h32[256];
  __shared__ float partLds[1536];
  __shared__ float bhL[768];
  if (t0 < 256) h32[t0] = 0.f;
  bhL[t0] = bhh_g[t0];
  if (t0 < 256) bhL[512+t0] = bhh_g[512+t0];
  float hprev = 0.f;
  __syncthreads();
  #pragma unroll 1
  for (int t=0;t<NTIME;t++){
    float gxr=0.f, gxz=0.f, gxn=0.f;
    if (t0 < 256){
      const float* gxp = gx + ((size_t)t*NBATCH + b)*768;
      gxr = gxp[t0]; gxz = gxp[256+t0]; gxn = gxp[512+t0];
    }
    // lane l owns h[4l..4l+3]; global pair p=(hf*64+jj) lives at lane hf*32+(jj>>1), reg jj&1
    float4 hq = *(const float4*)(h32 + 4*lane);
    int hpk0 = __builtin_bit_cast(int, pack2(hq.x, hq.y));
    int hpk1 = __builtin_bit_cast(int, pack2(hq.z, hq.w));
    #pragma unroll
    for (int s=0;s<3;s++){
      float a0=0.f, a1=0.f, a2=0.f, a3=0.f;
      #pragma unroll
      for (int jj=0;jj<64;jj+=2){
        int hv0 = __builtin_amdgcn_readlane(hpk0, hfb[s] + (jj>>1));
        int hv1 = __builtin_amdgcn_readlane(hpk1, hfb[s] + (jj>>1));
        if ((jj>>1)&1){
          a2 = dot2acc(wp[s][jj],   __builtin_bit_cast(half2_t, hv0), a2);
          a3 = dot2acc(wp[s][jj+1], __builtin_bit_cast(half2_t, hv1), a3);
        } else {
          a0 = dot2acc(wp[s][jj],   __builtin_bit_cast(half2_t, hv0), a0);
          a1 = dot2acc(wp[s][jj+1], __builtin_bit_cast(half2_t, hv1), a1);
        }
      }
      partLds[pidx[s]] = a0+a1+a2+a3;
    }
    __syncthreads();
    if (t0 < 256){
      float rh = bhL[t0]     + partLds[t0]     + partLds[768+t0];
      float zh = bhL[256+t0] + partLds[256+t0] + partLds[1024+t0];
      float nh = bhL[512+t0] + partLds[512+t0] + partLds[1280+t0];
      float r = sig_(gxr + rh);
      float z = sig_(gxz + zh);
      float n = tanh_(gxn + r*nh);
      float h = (1.f-z)*n + z*hprev;
      hprev = h;
      h32[t0] = h;
      hs[((size_t)t*NBATCH + b)*NCH + t0] = h;
    }
    __syncthreads();
  }
}

// ---------------- K6: logits for packed rows (fp32 SIMT, known-good) ----------------
__global__ __launch_bounds__(256) void k_logits(const float* __restrict__ hs, const int* __restrict__ pack_t,
    const int* __restrict__ pack_b, const float* __restrict__ W, const float* __restrict__ bias,
    float* __restrict__ out, int L){
  __shared__ float Xs[64*65];
  __shared__ float Ws[64*65];
  __shared__ int rt[64], rb[64];
  int m0 = blockIdx.y*64, n0 = blockIdx.x*64, tid = threadIdx.x;
  if (tid < 64){
    int m = m0 + tid;
    rt[tid] = (m<L) ? pack_t[m] : 0;
    rb[tid] = (m<L) ? pack_b[m] : 0;
  }
  float acc[4][4] = {};
  int rq = tid>>4, cq = tid&15;
  __syncthreads();
  for (int k0=0;k0<256;k0+=64){
    __syncthreads();
    #pragma unroll
    for (int j=0;j<4;j++){
      int f4 = j*256+tid, r = f4>>4, cc = (f4&15)*4;
      float4 vx = *(const float4*)(hs + ((size_t)rt[r]*NBATCH + rb[r])*NCH + k0 + cc);
      Xs[r*65+cc+0]=vx.x; Xs[r*65+cc+1]=vx.y; Xs[r*65+cc+2]=vx.z; Xs[r*65+cc+3]=vx.w;
      float4 vw = *(const float4*)(W + (size_t)(n0+r)*256 + k0 + cc);
      Ws[r*65+cc+0]=vw.x; Ws[r*65+cc+1]=vw.y; Ws[r*65+cc+2]=vw.z; Ws[r*65+cc+3]=vw.w;
    }
    __syncthreads();
    #pragma unroll 8
    for (int k=0;k<64;k++){
      float xa[4], wb[4];
      #pragma unroll
      for (int i=0;i<4;i++) xa[i] = Xs[(rq*4+i)*65+k];
      #pragma unroll
      for (int j=0;j<4;j++) wb[j] = Ws[(cq*4+j)*65+k];
      #pragma unroll
      for (int i=0;i<4;i++)
        #pragma unroll
        for (int j=0;j<4;j++) acc[i][j] += xa[i]*wb[j];
    }
  }
  float bs[4];
  #pragma unroll
  for (int j=0;j<4;j++) bs[j] = bias[n0+cq*4+j];
  #pragma unroll
  for (int i=0;i<4;i++){
    int m = m0 + rq*4 + i;
    if (m < L){
      float4 o; o.x=acc[i][0]+bs[0]; o.y=acc[i][1]+bs[1]; o.z=acc[i][2]+bs[2]; o.w=acc[i][3]+bs[3];
      *(float4*)(out + (size_t)m*NCLS + n0 + cq*4) = o;
    }
  }
}

extern "C" void kernel_launch(void* const* d_in, const int* in_sizes, int n_in,
                              void* d_out, int out_size, void* d_ws, size_t ws_size,
                              hipStream_t stream) {
  const float* feature = (const float*)d_in[0];
  const float* A       = (const float*)d_in[1];
  const int*   text    = (const int*)d_in[2];
  const int*   pack_b  = (const int*)d_in[4];
  const int*   pack_t  = (const int*)d_in[5];
  const float* emb     = (const float*)d_in[6];
  const float* Wih_f   = (const float*)d_in[7];
  const float* Whh_f   = (const float*)d_in[8];
  const float* bih_f   = (const float*)d_in[9];
  const float* bhh_f   = (const float*)d_in[10];
  const float* Wih_b   = (const float*)d_in[11];
  const float* Whh_b   = (const float*)d_in[12];
  const float* bih_b   = (const float*)d_in[13];
  const float* bhh_b   = (const float*)d_in[14];
  const float* Wih_g   = (const float*)d_in[15];
  const float* Whh_g   = (const float*)d_in[16];
  const float* bih_g   = (const float*)d_in[17];
  const float* bhh_g   = (const float*)d_in[18];
  const float* Wgen    = (const float*)d_in[19];
  const float* bgen    = (const float*)d_in[20];
  int L = in_sizes[4];

  char* ws = (char*)d_ws;
  const size_t MB = 1u<<20;
  float* S   = (float*)(ws + 0);
  float* C   = (float*)(ws + 1*MB);    // 8 MB  [t][b][256]
  float* Cl  = (float*)(ws + 9*MB);    // 8 MB  [t][b][256]
  float* hs  = (float*)(ws + 17*MB);   // 8 MB  [t][b][256]
  float* Gf  = (float*)(ws + 25*MB);   // 16 MB [t][b][512]  (dead after k_lstm)
  float* Gb  = (float*)(ws + 41*MB);   // 16 MB [t][b][512]  (dead after k_lstm)
  float* xs  = (float*)(ws + 25*MB);   // 16 MB, aliases Gf (written after k_lstm)
  float* gx  = (float*)(ws + 41*MB);   // 24 MB, aliases Gb (written after k_lstm)

  float* out_res   = (float*)d_out;
  float* out_attns = out_res + (size_t)L*NCLS;

  k_rowsum<<<8192, 256, 0, stream>>>(A, S);
  k_pool<<<dim3(128,4), 256, 0, stream>>>(feature, A, S, C);
  k_attns<<<L, 256, 0, stream>>>(A, S, pack_b, pack_t, out_attns);
  k_gemm_bias<<<dim3(8,128), 256, 0, stream>>>(C, Wih_f, bih_f, bhh_f, Gf, 512, 256);
  k_gemm_bias<<<dim3(8,128), 256, 0, stream>>>(C, Wih_b, bih_b, bhh_b, Gb, 512, 256);
  k_lstm<<<256, 512, 0, stream>>>(Gf, Gb, Whh_f, Whh_b, Cl);
  k_xs<<<4096, 256, 0, stream>>>(Cl, emb, text, xs);
  k_gemm_bias<<<dim3(12,128), 256, 0, stream>>>(xs, Wih_g, bih_g, nullptr, gx, 768, 512);
  k_gru<<<128, 512, 0, stream>>>(gx, Whh_g, bhh_g, hs);
  k_logits<<<dim3(2,(L+63)/64), 256, 0, stream>>>(hs, pack_t, pack_b, Wgen, bgen, out_res, L);
}

// Round 7
// 465.833 us; speedup vs baseline: 1.2916x; 1.1978x over previous
//
#include <hip/hip_runtime.h>
#include <cstdint>
#include <cstddef>

#define NBATCH 128
#define NCH    256
#define NHW    1024
#define NTIME  64
#define NCLS   128

typedef _Float16 half2_t __attribute__((ext_vector_type(2)));
typedef short bf16x8 __attribute__((ext_vector_type(8)));
typedef short bf16x4 __attribute__((ext_vector_type(4)));
typedef float f32x4 __attribute__((ext_vector_type(4)));
typedef unsigned short ushort_t;

#if defined(__has_builtin)
#  if __has_builtin(__builtin_amdgcn_fdot2)
#    define HAS_FDOT2 1
#  endif
#endif
#ifndef HAS_FDOT2
#  define HAS_FDOT2 0
#endif

__device__ __forceinline__ float dot2acc(half2_t a, half2_t b, float c){
#if HAS_FDOT2
  return __builtin_amdgcn_fdot2(a, b, c, false);
#else
  return c + (float)a.x*(float)b.x + (float)a.y*(float)b.y;
#endif
}
__device__ __forceinline__ half2_t pack2(float x, float y){
  half2_t p; p.x = (_Float16)x; p.y = (_Float16)y; return p;
}
__device__ __forceinline__ ushort_t f2bf(float x){
  unsigned u = __builtin_bit_cast(unsigned, x);
  unsigned r = (u + 0x7FFFu + ((u>>16)&1u)) >> 16;
  return (ushort_t)r;
}
__device__ __forceinline__ float sig_(float x){
  x = fminf(30.f, fmaxf(-30.f, x));
  return 1.f/(1.f+__expf(-x));
}
__device__ __forceinline__ float tanh_(float x){
  x = fminf(15.f, fmaxf(-15.f, x));
  float e = __expf(2.f*x);
  return (e-1.f)/(e+1.f);
}

// ---------------- K0: row sums of A -> S[b*64+t] ----------------
__global__ __launch_bounds__(256) void k_rowsum(const float* __restrict__ A, float* __restrict__ S){
  int row = blockIdx.x;
  const float4* a4 = (const float4*)(A + (size_t)row*NHW);
  float4 v = a4[threadIdx.x];
  float s = v.x+v.y+v.z+v.w;
  #pragma unroll
  for (int off=32; off>0; off>>=1) s += __shfl_down(s, off, 64);
  __shared__ float wsum[4];
  int lane = threadIdx.x & 63, w = threadIdx.x >> 6;
  if (lane==0) wsum[w] = s;
  __syncthreads();
  if (threadIdx.x==0) S[row] = wsum[0]+wsum[1]+wsum[2]+wsum[3];
}

// ---------------- weight fp32 -> bf16 convert ----------------
__global__ __launch_bounds__(256) void k_convw(const float* __restrict__ src, ushort_t* __restrict__ dst, int n){
  int i = blockIdx.x*256 + threadIdx.x;
  if (i < n) dst[i] = f2bf(src[i]);
}

// ---------------- K1: attention pooling via MFMA (R3 version, exonerated by R5) ------------
__global__ __launch_bounds__(256) void k_pool_mfma(const float* __restrict__ feat, const float* __restrict__ A,
    const float* __restrict__ S, ushort_t* __restrict__ Cbf){
  __shared__ ushort_t As_[64*40];
  __shared__ ushort_t Fs_[128*40];
  __shared__ float sinvs[64];
  int b = blockIdx.x >> 1, ch = blockIdx.x & 1, c0 = ch*128;
  int tid = threadIdx.x, wave = tid>>6, lane = tid&63;
  if (tid < 64) sinvs[tid] = 1.f / S[b*64 + tid];
  f32x4 acc[4][2] = {};
  int lr = lane & 15, lk = (lane>>4)*8;
  for (int k0=0;k0<NHW;k0+=32){
    __syncthreads();
    #pragma unroll
    for (int i=0;i<2;i++){
      int c = tid + i*256, r = c>>3, kq = c&7;
      float4 v = *(const float4*)(A + ((size_t)(b*64+r))*NHW + k0 + kq*4);
      bf16x4 p; p[0]=(short)f2bf(v.x); p[1]=(short)f2bf(v.y); p[2]=(short)f2bf(v.z); p[3]=(short)f2bf(v.w);
      *(bf16x4*)&As_[r*40 + kq*4] = p;
    }
    #pragma unroll
    for (int i=0;i<4;i++){
      int c = tid + i*256, r = c>>3, kq = c&7;
      float4 v = *(const float4*)(feat + ((size_t)(b*256+c0+r))*NHW + k0 + kq*4);
      bf16x4 p; p[0]=(short)f2bf(v.x); p[1]=(short)f2bf(v.y); p[2]=(short)f2bf(v.z); p[3]=(short)f2bf(v.w);
      *(bf16x4*)&Fs_[r*40 + kq*4] = p;
    }
    __syncthreads();
    bf16x8 af[4], bg[2];
    #pragma unroll
    for (int m=0;m<4;m++) af[m] = *(const bf16x8*)&As_[(m*16 + lr)*40 + lk];
    #pragma unroll
    for (int n=0;n<2;n++) bg[n] = *(const bf16x8*)&Fs_[(wave*32 + n*16 + lr)*40 + lk];
    #pragma unroll
    for (int m=0;m<4;m++)
      #pragma unroll
      for (int n=0;n<2;n++)
        acc[m][n] = __builtin_amdgcn_mfma_f32_16x16x32_bf16(af[m], bg[n], acc[m][n], 0, 0, 0);
  }
  #pragma unroll
  for (int m=0;m<4;m++)
    #pragma unroll
    for (int n=0;n<2;n++)
      #pragma unroll
      for (int j=0;j<4;j++){
        int t = m*16 + (lane>>4)*4 + j;
        int c = c0 + wave*32 + n*16 + lr;
        Cbf[((size_t)t*NBATCH + b)*NCH + c] = f2bf(acc[m][n][j] * sinvs[t]);
      }
}

// ---------------- generic bf16 MFMA GEMM: out[M][N]fp32 = Xbf[M][K] @ Wbf[N][K]^T + ba(+bb) ---
__global__ __launch_bounds__(256) void k_gemm_bf(const ushort_t* __restrict__ X, const ushort_t* __restrict__ W,
    const float* __restrict__ ba, const float* __restrict__ bb, float* __restrict__ out, int N, int K){
  __shared__ ushort_t Xs[128*40];
  __shared__ ushort_t Ws[128*40];
  int n0 = blockIdx.x*128, m0 = blockIdx.y*128;
  int tid = threadIdx.x, wave = tid>>6, lane = tid&63;
  int wr = wave>>1, wc = wave&1;
  int lr = lane & 15, lk = (lane>>4)*8;
  f32x4 acc[4][4] = {};
  for (int k0=0;k0<K;k0+=32){
    __syncthreads();
    #pragma unroll
    for (int i=0;i<2;i++){
      int c = tid + i*256, r = c>>2, kb = c&3;
      *(bf16x8*)&Xs[r*40 + kb*8] = *(const bf16x8*)(X + (size_t)(m0+r)*K + k0 + kb*8);
      *(bf16x8*)&Ws[r*40 + kb*8] = *(const bf16x8*)(W + (size_t)(n0+r)*K + k0 + kb*8);
    }
    __syncthreads();
    bf16x8 af[4], bg[4];
    #pragma unroll
    for (int m=0;m<4;m++) af[m] = *(const bf16x8*)&Xs[(wr*64 + m*16 + lr)*40 + lk];
    #pragma unroll
    for (int n=0;n<4;n++) bg[n] = *(const bf16x8*)&Ws[(wc*64 + n*16 + lr)*40 + lk];
    #pragma unroll
    for (int m=0;m<4;m++)
      #pragma unroll
      for (int n=0;n<4;n++)
        acc[m][n] = __builtin_amdgcn_mfma_f32_16x16x32_bf16(af[m], bg[n], acc[m][n], 0, 0, 0);
  }
  float bsv[4];
  #pragma unroll
  for (int n=0;n<4;n++){
    int col = n0 + wc*64 + n*16 + lr;
    bsv[n] = ba[col] + (bb ? bb[col] : 0.f);
  }
  #pragma unroll
  for (int m=0;m<4;m++)
    #pragma unroll
    for (int n=0;n<4;n++)
      #pragma unroll
      for (int j=0;j<4;j++){
        int row = m0 + wr*64 + m*16 + (lane>>4)*4 + j;
        int col = n0 + wc*64 + n*16 + lr;
        out[(size_t)row*N + col] = acc[m][n][j] + bsv[n];
      }
}

// ---------------- K7: packed normalized attention output ----------------
__global__ __launch_bounds__(256) void k_attns(const float* __restrict__ A, const float* __restrict__ S,
    const int* __restrict__ pack_b, const int* __restrict__ pack_t, float* __restrict__ outA){
  int i = blockIdx.x;
  int b = pack_b[i], t = pack_t[i];
  float is = 1.f / S[b*64 + t];
  float4 v = ((const float4*)(A + ((size_t)(b*64+t))*NHW))[threadIdx.x];
  v.x*=is; v.y*=is; v.z*=is; v.w*=is;
  ((float4*)(outA + (size_t)i*NHW))[threadIdx.x] = v;
}

// ---------------- K3: BiLSTM scan (R6-passing), bf16 output ----------------
__global__ __launch_bounds__(512, 2) void k_lstm(const float* __restrict__ Gf, const float* __restrict__ Gb,
    const float* __restrict__ Whh_f, const float* __restrict__ Whh_b, ushort_t* __restrict__ Clbf){
  int b = blockIdx.x & 127, dir = blockIdx.x >> 7;
  int g = threadIdx.x, lane = g & 63;
  const float* Whh = dir ? Whh_b : Whh_f;
  const float* G   = dir ? Gb    : Gf;
  half2_t wp[64];
  {
    const float4* wr = (const float4*)(Whh + (size_t)g*128);
    #pragma unroll
    for (int j=0;j<32;j++){
      float4 v = wr[j];
      wp[2*j]   = pack2(v.x, v.y);
      wp[2*j+1] = pack2(v.z, v.w);
    }
  }
  __shared__ float h32[128];
  __shared__ float gates[512];
  if (g < 128) h32[g] = 0.f;
  float c = 0.f;
  __syncthreads();
  #pragma unroll 1
  for (int t=0;t<NTIME;t++){
    int tt = dir ? (NTIME-1-t) : t;
    float gv = G[((size_t)tt*NBATCH + b)*512 + g];
    float2 hp2 = *(const float2*)(h32 + 2*lane);
    int hpk = __builtin_bit_cast(int, pack2(hp2.x, hp2.y));
    float acc[4] = {0.f,0.f,0.f,0.f};
    #pragma unroll
    for (int p=0;p<64;p++){
      int hv = __builtin_amdgcn_readlane(hpk, p);
      acc[p&3] = dot2acc(wp[p], __builtin_bit_cast(half2_t, hv), acc[p&3]);
    }
    gates[g] = gv + acc[0]+acc[1]+acc[2]+acc[3];
    __syncthreads();
    if (g < 128){
      float gi=gates[g], gf=gates[128+g], gg=gates[256+g], go=gates[384+g];
      c = sig_(gf)*c + sig_(gi)*tanh_(gg);
      float h = sig_(go)*tanh_(c);
      h32[g] = h;
      Clbf[((size_t)tt*NBATCH + b)*NCH + dir*128 + g] = f2bf(h);
    }
    __syncthreads();
  }
}

// ---------------- K4a: xs(bf16) = [Cl_bf | emb->bf16] ----------------
__global__ __launch_bounds__(256) void k_xs(const ushort_t* __restrict__ Clbf, const float* __restrict__ emb,
    const int* __restrict__ text, ushort_t* __restrict__ xsbf){
  int idx = blockIdx.x*256 + threadIdx.x;       // 8-elem chunks: 8192 rows x 64
  int row = idx>>6, c8 = idx&63;
  int t = row>>7, b = row&127;
  bf16x8 v;
  if (c8 < 32) v = *(const bf16x8*)(Clbf + (size_t)row*NCH + c8*8);
  else {
    int cls = (t==0) ? 0 : text[b*64 + (t-1)];
    const float4* e4 = (const float4*)(emb + (size_t)cls*NCH + (c8-32)*8);
    float4 a = e4[0], bq = e4[1];
    v[0]=(short)f2bf(a.x);  v[1]=(short)f2bf(a.y);  v[2]=(short)f2bf(a.z);  v[3]=(short)f2bf(a.w);
    v[4]=(short)f2bf(bq.x); v[5]=(short)f2bf(bq.y); v[6]=(short)f2bf(bq.z); v[7]=(short)f2bf(bq.w);
  }
  *(bf16x8*)(xsbf + (size_t)row*512 + c8*8) = v;
}

// ---------------- K5: GRU scan, 1024 threads, 96 weight VGPRs/thread ----------------
// 3072 tasks = 768 rows x 4 k-quarters (64 cols). chunk c = wave*3+s; q=c/12 (wave-uniform),
// row=(c%12)*64+lane. h pair p=q*32+u lives at lane q*16+(u>>1), reg u&1.
__global__ __launch_bounds__(1024, 4) void k_gru(const float* __restrict__ gx,
    const float* __restrict__ Whh_g, const float* __restrict__ bhh_g, ushort_t* __restrict__ hsbf){
  int b = blockIdx.x, t0 = threadIdx.x, lane = t0 & 63, w = t0 >> 6;
  half2_t wp[3][32];
  int pidx[3];   // partLds index = q*768 + row
  int q16[3];    // readlane base = q*16 (SGPR)
  #pragma unroll
  for (int s=0;s<3;s++){
    int c = w*3 + s;                  // 0..47
    int q = c/12, rg = c - q*12;      // q 0..3, rg 0..11
    int row = rg*64 + lane;           // 0..767
    pidx[s] = q*768 + row;
    q16[s]  = __builtin_amdgcn_readfirstlane(q*16);
    const float4* wr = (const float4*)(Whh_g + (size_t)row*256 + q*64);
    #pragma unroll
    for (int j=0;j<16;j++){
      float4 v = wr[j];
      wp[s][2*j]   = pack2(v.x, v.y);
      wp[s][2*j+1] = pack2(v.z, v.w);
    }
  }
  __shared__ float h32[256];
  __shared__ float partLds[3072];
  __shared__ float bhL[768];
  if (t0 < 256) h32[t0] = 0.f;
  if (t0 < 768) bhL[t0] = bhh_g[t0];
  float hprev = 0.f;
  __syncthreads();
  #pragma unroll 1
  for (int t=0;t<NTIME;t++){
    float gxr=0.f, gxz=0.f, gxn=0.f;
    if (t0 < 256){
      const float* gxp = gx + ((size_t)t*NBATCH + b)*768;
      gxr = gxp[t0]; gxz = gxp[256+t0]; gxn = gxp[512+t0];
    }
    // lane l holds h[4l..4l+3] as pairs 2l (hpk0) and 2l+1 (hpk1)
    float4 hq = *(const float4*)(h32 + 4*lane);
    int hpk0 = __builtin_bit_cast(int, pack2(hq.x, hq.y));
    int hpk1 = __builtin_bit_cast(int, pack2(hq.z, hq.w));
    #pragma unroll
    for (int s=0;s<3;s++){
      float a0=0.f, a1=0.f, a2=0.f, a3=0.f;
      #pragma unroll
      for (int u=0;u<32;u+=4){
        int h0 = __builtin_amdgcn_readlane(hpk0, q16[s] + (u>>1));
        int h1 = __builtin_amdgcn_readlane(hpk1, q16[s] + (u>>1));
        int h2 = __builtin_amdgcn_readlane(hpk0, q16[s] + (u>>1) + 1);
        int h3 = __builtin_amdgcn_readlane(hpk1, q16[s] + (u>>1) + 1);
        a0 = dot2acc(wp[s][u],   __builtin_bit_cast(half2_t, h0), a0);
        a1 = dot2acc(wp[s][u+1], __builtin_bit_cast(half2_t, h1), a1);
        a2 = dot2acc(wp[s][u+2], __builtin_bit_cast(half2_t, h2), a2);
        a3 = dot2acc(wp[s][u+3], __builtin_bit_cast(half2_t, h3), a3);
      }
      partLds[pidx[s]] = a0+a1+a2+a3;
    }
    __syncthreads();
    if (t0 < 256){
      float rh = bhL[t0]     + partLds[t0]     + partLds[768+t0]      + partLds[1536+t0]      + partLds[2304+t0];
      float zh = bhL[256+t0] + partLds[256+t0] + partLds[768+256+t0]  + partLds[1536+256+t0]  + partLds[2304+256+t0];
      float nh = bhL[512+t0] + partLds[512+t0] + partLds[768+512+t0]  + partLds[1536+512+t0]  + partLds[2304+512+t0];
      float r = sig_(gxr + rh);
      float z = sig_(gxz + zh);
      float n = tanh_(gxn + r*nh);
      float h = (1.f-z)*n + z*hprev;
      hprev = h;
      h32[t0] = h;
      hsbf[((size_t)t*NBATCH + b)*NCH + t0] = f2bf(h);
    }
    __syncthreads();
  }
}

// ---------------- K6: logits via MFMA with row gather (R3 version, exonerated) ----------------
__global__ __launch_bounds__(256) void k_logits_mfma(const ushort_t* __restrict__ hsbf,
    const int* __restrict__ pack_t, const int* __restrict__ pack_b,
    const ushort_t* __restrict__ Wbf, const float* __restrict__ bias,
    float* __restrict__ out, int L){
  __shared__ ushort_t Xs[64*40];
  __shared__ ushort_t Ws[128*40];
  __shared__ int rrow[64];
  int m0 = blockIdx.x*64;
  int tid = threadIdx.x, wave = tid>>6, lane = tid&63;
  int lr = lane & 15, lk = (lane>>4)*8;
  if (tid < 64){
    int m = m0 + tid;
    int pt = (m<L) ? pack_t[m] : 0;
    int pb = (m<L) ? pack_b[m] : 0;
    rrow[tid] = pt*NBATCH + pb;
  }
  f32x4 acc[4][2] = {};
  for (int k0=0;k0<NCH;k0+=32){
    __syncthreads();
    {
      int r = tid>>2, kb = tid&3;
      *(bf16x8*)&Xs[r*40 + kb*8] = *(const bf16x8*)(hsbf + (size_t)rrow[r]*NCH + k0 + kb*8);
    }
    #pragma unroll
    for (int i=0;i<2;i++){
      int c = tid + i*256, r = c>>2, kb = c&3;
      *(bf16x8*)&Ws[r*40 + kb*8] = *(const bf16x8*)(Wbf + (size_t)r*NCH + k0 + kb*8);
    }
    __syncthreads();
    bf16x8 af[4], bg[2];
    #pragma unroll
    for (int m=0;m<4;m++) af[m] = *(const bf16x8*)&Xs[(m*16 + lr)*40 + lk];
    #pragma unroll
    for (int n=0;n<2;n++) bg[n] = *(const bf16x8*)&Ws[(wave*32 + n*16 + lr)*40 + lk];
    #pragma unroll
    for (int m=0;m<4;m++)
      #pragma unroll
      for (int n=0;n<2;n++)
        acc[m][n] = __builtin_amdgcn_mfma_f32_16x16x32_bf16(af[m], bg[n], acc[m][n], 0, 0, 0);
  }
  #pragma unroll
  for (int m=0;m<4;m++)
    #pragma unroll
    for (int n=0;n<2;n++)
      #pragma unroll
      for (int j=0;j<4;j++){
        int row = m0 + m*16 + (lane>>4)*4 + j;
        int col = wave*32 + n*16 + lr;
        if (row < L) out[(size_t)row*NCLS + col] = acc[m][n][j] + bias[col];
      }
}

extern "C" void kernel_launch(void* const* d_in, const int* in_sizes, int n_in,
                              void* d_out, int out_size, void* d_ws, size_t ws_size,
                              hipStream_t stream) {
  const float* feature = (const float*)d_in[0];
  const float* A       = (const float*)d_in[1];
  const int*   text    = (const int*)d_in[2];
  const int*   pack_b  = (const int*)d_in[4];
  const int*   pack_t  = (const int*)d_in[5];
  const float* emb     = (const float*)d_in[6];
  const float* Wih_f   = (const float*)d_in[7];
  const float* Whh_f   = (const float*)d_in[8];
  const float* bih_f   = (const float*)d_in[9];
  const float* bhh_f   = (const float*)d_in[10];
  const float* Wih_b   = (const float*)d_in[11];
  const float* Whh_b   = (const float*)d_in[12];
  const float* bih_b   = (const float*)d_in[13];
  const float* bhh_b   = (const float*)d_in[14];
  const float* Wih_g   = (const float*)d_in[15];
  const float* Whh_g   = (const float*)d_in[16];
  const float* bih_g   = (const float*)d_in[17];
  const float* bhh_g   = (const float*)d_in[18];
  const float* Wgen    = (const float*)d_in[19];
  const float* bgen    = (const float*)d_in[20];
  int L = in_sizes[4];

  char* ws = (char*)d_ws;
  const size_t MB = 1u<<20;
  float*    S       = (float*)(ws + 0);                    // 32 KB
  ushort_t* Wf_bf   = (ushort_t*)(ws + 1*MB);              // 256 KB
  ushort_t* Wb_bf   = (ushort_t*)(ws + 1*MB + 256*1024);   // 256 KB
  ushort_t* Wg_bf   = (ushort_t*)(ws + 1*MB + 512*1024);   // 768 KB
  ushort_t* Wgen_bf = (ushort_t*)(ws + 1*MB + 1280*1024);  // 64 KB
  ushort_t* Cbf     = (ushort_t*)(ws + 3*MB);              // 4 MB  [t][b][256]
  ushort_t* Clbf    = (ushort_t*)(ws + 7*MB);              // 4 MB
  ushort_t* hsbf    = (ushort_t*)(ws + 11*MB);             // 4 MB
  float*    Gf      = (float*)(ws + 16*MB);                // 16 MB (dead after k_lstm)
  float*    Gb      = (float*)(ws + 32*MB);                // 16 MB (dead after k_lstm)
  ushort_t* xsbf    = (ushort_t*)(ws + 16*MB);             // 8 MB, aliases Gf
  float*    gx      = (float*)(ws + 24*MB);                // 25.2 MB, aliases Gb+

  float* out_res   = (float*)d_out;
  float* out_attns = out_res + (size_t)L*NCLS;

  k_convw<<<512, 256, 0, stream>>>(Wih_f, Wf_bf, 512*256);
  k_convw<<<512, 256, 0, stream>>>(Wih_b, Wb_bf, 512*256);
  k_convw<<<1536, 256, 0, stream>>>(Wih_g, Wg_bf, 768*512);
  k_convw<<<128, 256, 0, stream>>>(Wgen, Wgen_bf, 128*256);
  k_rowsum<<<8192, 256, 0, stream>>>(A, S);
  k_pool_mfma<<<256, 256, 0, stream>>>(feature, A, S, Cbf);
  k_attns<<<L, 256, 0, stream>>>(A, S, pack_b, pack_t, out_attns);
  k_gemm_bf<<<dim3(4,64), 256, 0, stream>>>(Cbf, Wf_bf, bih_f, bhh_f, Gf, 512, 256);
  k_gemm_bf<<<dim3(4,64), 256, 0, stream>>>(Cbf, Wb_bf, bih_b, bhh_b, Gb, 512, 256);
  k_lstm<<<256, 512, 0, stream>>>(Gf, Gb, Whh_f, Whh_b, Clbf);
  k_xs<<<2048, 256, 0, stream>>>(Clbf, emb, text, xsbf);
  k_gemm_bf<<<dim3(6,64), 256, 0, stream>>>(xsbf, Wg_bf, bih_g, nullptr, gx, 768, 512);
  k_gru<<<128, 1024, 0, stream>>>(gx, Whh_g, bhh_g, hsbf);
  k_logits_mfma<<<(L+63)/64, 256, 0, stream>>>(hsbf, pack_t, pack_b, Wgen_bf, bgen, out_res, L);
}

// Round 9
// 394.865 us; speedup vs baseline: 1.5237x; 1.1797x over previous
//
#include <hip/hip_runtime.h>
#include <cstdint>
#include <cstddef>

#define NBATCH 128
#define NCH    256
#define NHW    1024
#define NTIME  64
#define NCLS   128

typedef _Float16 half2_t __attribute__((ext_vector_type(2)));
typedef short bf16x8 __attribute__((ext_vector_type(8)));
typedef short bf16x4 __attribute__((ext_vector_type(4)));
typedef float f32x4 __attribute__((ext_vector_type(4)));
typedef unsigned short ushort_t;

#if defined(__has_builtin)
#  if __has_builtin(__builtin_amdgcn_fdot2)
#    define HAS_FDOT2 1
#  endif
#endif
#ifndef HAS_FDOT2
#  define HAS_FDOT2 0
#endif

__device__ __forceinline__ float dot2acc(half2_t a, half2_t b, float c){
#if HAS_FDOT2
  return __builtin_amdgcn_fdot2(a, b, c, false);
#else
  return c + (float)a.x*(float)b.x + (float)a.y*(float)b.y;
#endif
}
__device__ __forceinline__ half2_t pack2(float x, float y){
  half2_t p; p.x = (_Float16)x; p.y = (_Float16)y; return p;
}
__device__ __forceinline__ ushort_t f2bf(float x){
  unsigned u = __builtin_bit_cast(unsigned, x);
  unsigned r = (u + 0x7FFFu + ((u>>16)&1u)) >> 16;
  return (ushort_t)r;
}
__device__ __forceinline__ float sig_(float x){
  x = fminf(30.f, fmaxf(-30.f, x));
  return 1.f/(1.f+__expf(-x));
}
__device__ __forceinline__ float tanh_(float x){
  x = fminf(15.f, fmaxf(-15.f, x));
  float e = __expf(2.f*x);
  return (e-1.f)/(e+1.f);
}

// ---------------- K0: row sums of A -> S[b*64+t] ----------------
__global__ __launch_bounds__(256) void k_rowsum(const float* __restrict__ A, float* __restrict__ S){
  int row = blockIdx.x;
  const float4* a4 = (const float4*)(A + (size_t)row*NHW);
  float4 v = a4[threadIdx.x];
  float s = v.x+v.y+v.z+v.w;
  #pragma unroll
  for (int off=32; off>0; off>>=1) s += __shfl_down(s, off, 64);
  __shared__ float wsum[4];
  int lane = threadIdx.x & 63, w = threadIdx.x >> 6;
  if (lane==0) wsum[w] = s;
  __syncthreads();
  if (threadIdx.x==0) S[row] = wsum[0]+wsum[1]+wsum[2]+wsum[3];
}

// ---------------- weight fp32 -> bf16 convert ----------------
__global__ __launch_bounds__(256) void k_convw(const float* __restrict__ src, ushort_t* __restrict__ dst, int n){
  int i = blockIdx.x*256 + threadIdx.x;
  if (i < n) dst[i] = f2bf(src[i]);
}

// ---------------- K1: attention pooling via MFMA ----------------
__global__ __launch_bounds__(256) void k_pool_mfma(const float* __restrict__ feat, const float* __restrict__ A,
    const float* __restrict__ S, ushort_t* __restrict__ Cbf){
  __shared__ ushort_t As_[64*40];
  __shared__ ushort_t Fs_[128*40];
  __shared__ float sinvs[64];
  int b = blockIdx.x >> 1, ch = blockIdx.x & 1, c0 = ch*128;
  int tid = threadIdx.x, wave = tid>>6, lane = tid&63;
  if (tid < 64) sinvs[tid] = 1.f / S[b*64 + tid];
  f32x4 acc[4][2] = {};
  int lr = lane & 15, lk = (lane>>4)*8;
  for (int k0=0;k0<NHW;k0+=32){
    __syncthreads();
    #pragma unroll
    for (int i=0;i<2;i++){
      int c = tid + i*256, r = c>>3, kq = c&7;
      float4 v = *(const float4*)(A + ((size_t)(b*64+r))*NHW + k0 + kq*4);
      bf16x4 p; p[0]=(short)f2bf(v.x); p[1]=(short)f2bf(v.y); p[2]=(short)f2bf(v.z); p[3]=(short)f2bf(v.w);
      *(bf16x4*)&As_[r*40 + kq*4] = p;
    }
    #pragma unroll
    for (int i=0;i<4;i++){
      int c = tid + i*256, r = c>>3, kq = c&7;
      float4 v = *(const float4*)(feat + ((size_t)(b*256+c0+r))*NHW + k0 + kq*4);
      bf16x4 p; p[0]=(short)f2bf(v.x); p[1]=(short)f2bf(v.y); p[2]=(short)f2bf(v.z); p[3]=(short)f2bf(v.w);
      *(bf16x4*)&Fs_[r*40 + kq*4] = p;
    }
    __syncthreads();
    bf16x8 af[4], bg[2];
    #pragma unroll
    for (int m=0;m<4;m++) af[m] = *(const bf16x8*)&As_[(m*16 + lr)*40 + lk];
    #pragma unroll
    for (int n=0;n<2;n++) bg[n] = *(const bf16x8*)&Fs_[(wave*32 + n*16 + lr)*40 + lk];
    #pragma unroll
    for (int m=0;m<4;m++)
      #pragma unroll
      for (int n=0;n<2;n++)
        acc[m][n] = __builtin_amdgcn_mfma_f32_16x16x32_bf16(af[m], bg[n], acc[m][n], 0, 0, 0);
  }
  #pragma unroll
  for (int m=0;m<4;m++)
    #pragma unroll
    for (int n=0;n<2;n++)
      #pragma unroll
      for (int j=0;j<4;j++){
        int t = m*16 + (lane>>4)*4 + j;
        int c = c0 + wave*32 + n*16 + lr;
        Cbf[((size_t)t*NBATCH + b)*NCH + c] = f2bf(acc[m][n][j] * sinvs[t]);
      }
}

// ---------------- generic bf16 MFMA GEMM: out[M][N]fp32 = Xbf[M][K] @ Wbf[N][K]^T + ba(+bb) ---
__global__ __launch_bounds__(256) void k_gemm_bf(const ushort_t* __restrict__ X, const ushort_t* __restrict__ W,
    const float* __restrict__ ba, const float* __restrict__ bb, float* __restrict__ out, int N, int K){
  __shared__ ushort_t Xs[128*40];
  __shared__ ushort_t Ws[128*40];
  int n0 = blockIdx.x*128, m0 = blockIdx.y*128;
  int tid = threadIdx.x, wave = tid>>6, lane = tid&63;
  int wr = wave>>1, wc = wave&1;
  int lr = lane & 15, lk = (lane>>4)*8;
  f32x4 acc[4][4] = {};
  for (int k0=0;k0<K;k0+=32){
    __syncthreads();
    #pragma unroll
    for (int i=0;i<2;i++){
      int c = tid + i*256, r = c>>2, kb = c&3;
      *(bf16x8*)&Xs[r*40 + kb*8] = *(const bf16x8*)(X + (size_t)(m0+r)*K + k0 + kb*8);
      *(bf16x8*)&Ws[r*40 + kb*8] = *(const bf16x8*)(W + (size_t)(n0+r)*K + k0 + kb*8);
    }
    __syncthreads();
    bf16x8 af[4], bg[4];
    #pragma unroll
    for (int m=0;m<4;m++) af[m] = *(const bf16x8*)&Xs[(wr*64 + m*16 + lr)*40 + lk];
    #pragma unroll
    for (int n=0;n<4;n++) bg[n] = *(const bf16x8*)&Ws[(wc*64 + n*16 + lr)*40 + lk];
    #pragma unroll
    for (int m=0;m<4;m++)
      #pragma unroll
      for (int n=0;n<4;n++)
        acc[m][n] = __builtin_amdgcn_mfma_f32_16x16x32_bf16(af[m], bg[n], acc[m][n], 0, 0, 0);
  }
  float bsv[4];
  #pragma unroll
  for (int n=0;n<4;n++){
    int col = n0 + wc*64 + n*16 + lr;
    bsv[n] = ba[col] + (bb ? bb[col] : 0.f);
  }
  #pragma unroll
  for (int m=0;m<4;m++)
    #pragma unroll
    for (int n=0;n<4;n++)
      #pragma unroll
      for (int j=0;j<4;j++){
        int row = m0 + wr*64 + m*16 + (lane>>4)*4 + j;
        int col = n0 + wc*64 + n*16 + lr;
        out[(size_t)row*N + col] = acc[m][n][j] + bsv[n];
      }
}

// ---------------- K7: packed normalized attention output ----------------
__global__ __launch_bounds__(256) void k_attns(const float* __restrict__ A, const float* __restrict__ S,
    const int* __restrict__ pack_b, const int* __restrict__ pack_t, float* __restrict__ outA){
  int i = blockIdx.x;
  int b = pack_b[i], t = pack_t[i];
  float is = 1.f / S[b*64 + t];
  float4 v = ((const float4*)(A + ((size_t)(b*64+t))*NHW))[threadIdx.x];
  v.x*=is; v.y*=is; v.z*=is; v.w*=is;
  ((float4*)(outA + (size_t)i*NHW))[threadIdx.x] = v;
}

// ---------------- K3: BiLSTM scan (R6-passing), bf16 output ----------------
__global__ __launch_bounds__(512, 2) void k_lstm(const float* __restrict__ Gf, const float* __restrict__ Gb,
    const float* __restrict__ Whh_f, const float* __restrict__ Whh_b, ushort_t* __restrict__ Clbf){
  int b = blockIdx.x & 127, dir = blockIdx.x >> 7;
  int g = threadIdx.x, lane = g & 63;
  const float* Whh = dir ? Whh_b : Whh_f;
  const float* G   = dir ? Gb    : Gf;
  half2_t wp[64];
  {
    const float4* wr = (const float4*)(Whh + (size_t)g*128);
    #pragma unroll
    for (int j=0;j<32;j++){
      float4 v = wr[j];
      wp[2*j]   = pack2(v.x, v.y);
      wp[2*j+1] = pack2(v.z, v.w);
    }
  }
  __shared__ float h32[128];
  __shared__ float gates[512];
  if (g < 128) h32[g] = 0.f;
  float c = 0.f;
  __syncthreads();
  #pragma unroll 1
  for (int t=0;t<NTIME;t++){
    int tt = dir ? (NTIME-1-t) : t;
    float gv = G[((size_t)tt*NBATCH + b)*512 + g];
    float2 hp2 = *(const float2*)(h32 + 2*lane);
    int hpk = __builtin_bit_cast(int, pack2(hp2.x, hp2.y));
    float acc[4] = {0.f,0.f,0.f,0.f};
    #pragma unroll
    for (int p=0;p<64;p++){
      int hv = __builtin_amdgcn_readlane(hpk, p);
      acc[p&3] = dot2acc(wp[p], __builtin_bit_cast(half2_t, hv), acc[p&3]);
    }
    gates[g] = gv + acc[0]+acc[1]+acc[2]+acc[3];
    __syncthreads();
    if (g < 128){
      float gi=gates[g], gf=gates[128+g], gg=gates[256+g], go=gates[384+g];
      c = sig_(gf)*c + sig_(gi)*tanh_(gg);
      float h = sig_(go)*tanh_(c);
      h32[g] = h;
      Clbf[((size_t)tt*NBATCH + b)*NCH + dir*128 + g] = f2bf(h);
    }
    __syncthreads();
  }
}

// ---------------- K4a: xs(bf16) = [Cl_bf | emb->bf16] ----------------
__global__ __launch_bounds__(256) void k_xs(const ushort_t* __restrict__ Clbf, const float* __restrict__ emb,
    const int* __restrict__ text, ushort_t* __restrict__ xsbf){
  int idx = blockIdx.x*256 + threadIdx.x;       // 8-elem chunks: 8192 rows x 64
  int row = idx>>6, c8 = idx&63;
  int t = row>>7, b = row&127;
  bf16x8 v;
  if (c8 < 32) v = *(const bf16x8*)(Clbf + (size_t)row*NCH + c8*8);
  else {
    int cls = (t==0) ? 0 : text[b*64 + (t-1)];
    const float4* e4 = (const float4*)(emb + (size_t)cls*NCH + (c8-32)*8);
    float4 a = e4[0], bq = e4[1];
    v[0]=(short)f2bf(a.x);  v[1]=(short)f2bf(a.y);  v[2]=(short)f2bf(a.z);  v[3]=(short)f2bf(a.w);
    v[4]=(short)f2bf(bq.x); v[5]=(short)f2bf(bq.y); v[6]=(short)f2bf(bq.z); v[7]=(short)f2bf(bq.w);
  }
  *(bf16x8*)(xsbf + (size_t)row*512 + c8*8) = v;
}

// ---------------- K5: GRU scan, 512 threads, (512,1) -> up to 256 VGPR @ 8 waves/CU ---------
// 1536 tasks = 768 rows x 2 k-halves(128 cols). Task c = w*3+s, s in {0,1,2} (named arrays),
// hf = c>=12 (wave-uniform), row = (c-hf*12)*64+lane. 192 weight VGPRs + ~50 working.
__global__ __launch_bounds__(512, 1) void k_gru(const float* __restrict__ gx,
    const float* __restrict__ Whh_g, const float* __restrict__ bhh_g, ushort_t* __restrict__ hsbf){
  int b = blockIdx.x, t0 = threadIdx.x, lane = t0 & 63, w = t0 >> 6;
  half2_t wpA[64], wpB[64], wpC[64];
  int pidxA, pidxB, pidxC;
  int hfbA, hfbB, hfbC;

#define LOADW(WP, PIDX, HFB, S) do { \
    int c = w*3 + (S); \
    int hf = (c >= 12) ? 1 : 0; \
    int row = (c - hf*12)*64 + lane; \
    PIDX = hf*768 + row; \
    HFB  = __builtin_amdgcn_readfirstlane(hf*32); \
    const float4* wr = (const float4*)(Whh_g + (size_t)row*256 + hf*128); \
    _Pragma("unroll") \
    for (int j=0;j<32;j++){ \
      float4 v = wr[j]; \
      WP[2*j]   = pack2(v.x, v.y); \
      WP[2*j+1] = pack2(v.z, v.w); \
    } \
  } while(0)

  LOADW(wpA, pidxA, hfbA, 0);
  LOADW(wpB, pidxB, hfbB, 1);
  LOADW(wpC, pidxC, hfbC, 2);
#undef LOADW

  __shared__ float h32[256];
  __shared__ float partLds[1536];
  __shared__ float bhL[768];
  if (t0 < 256) h32[t0] = 0.f;
  bhL[t0] = bhh_g[t0];
  if (t0 < 256) bhL[512+t0] = bhh_g[512+t0];
  float hprev = 0.f;
  __syncthreads();
  #pragma unroll 1
  for (int t=0;t<NTIME;t++){
    float gxr=0.f, gxz=0.f, gxn=0.f;
    if (t0 < 256){
      const float* gxp = gx + ((size_t)t*NBATCH + b)*768;
      gxr = gxp[t0]; gxz = gxp[256+t0]; gxn = gxp[512+t0];
    }
    // lane l holds h[4l..4l+3] as pairs 2l (hpk0) and 2l+1 (hpk1);
    // global pair P=hf*64+jj -> lane hf*32+(jj>>1), reg jj&1
    float4 hq = *(const float4*)(h32 + 4*lane);
    int hpk0 = __builtin_bit_cast(int, pack2(hq.x, hq.y));
    int hpk1 = __builtin_bit_cast(int, pack2(hq.z, hq.w));

#define DOTASK(WP, PIDX, HFB) do { \
    float a0=0.f, a1=0.f, a2=0.f, a3=0.f; \
    _Pragma("unroll") \
    for (int jj=0;jj<64;jj+=2){ \
      int hv0 = __builtin_amdgcn_readlane(hpk0, HFB + (jj>>1)); \
      int hv1 = __builtin_amdgcn_readlane(hpk1, HFB + (jj>>1)); \
      if ((jj>>1)&1){ \
        a2 = dot2acc(WP[jj],   __builtin_bit_cast(half2_t, hv0), a2); \
        a3 = dot2acc(WP[jj+1], __builtin_bit_cast(half2_t, hv1), a3); \
      } else { \
        a0 = dot2acc(WP[jj],   __builtin_bit_cast(half2_t, hv0), a0); \
        a1 = dot2acc(WP[jj+1], __builtin_bit_cast(half2_t, hv1), a1); \
      } \
    } \
    partLds[PIDX] = a0+a1+a2+a3; \
  } while(0)

    DOTASK(wpA, pidxA, hfbA);
    DOTASK(wpB, pidxB, hfbB);
    DOTASK(wpC, pidxC, hfbC);
#undef DOTASK

    __syncthreads();
    if (t0 < 256){
      float rh = bhL[t0]     + partLds[t0]     + partLds[768+t0];
      float zh = bhL[256+t0] + partLds[256+t0] + partLds[1024+t0];
      float nh = bhL[512+t0] + partLds[512+t0] + partLds[1280+t0];
      float r = sig_(gxr + rh);
      float z = sig_(gxz + zh);
      float n = tanh_(gxn + r*nh);
      float h = (1.f-z)*n + z*hprev;
      hprev = h;
      h32[t0] = h;
      hsbf[((size_t)t*NBATCH + b)*NCH + t0] = f2bf(h);
    }
    __syncthreads();
  }
}

// ---------------- K6: logits via MFMA with row gather ----------------
__global__ __launch_bounds__(256) void k_logits_mfma(const ushort_t* __restrict__ hsbf,
    const int* __restrict__ pack_t, const int* __restrict__ pack_b,
    const ushort_t* __restrict__ Wbf, const float* __restrict__ bias,
    float* __restrict__ out, int L){
  __shared__ ushort_t Xs[64*40];
  __shared__ ushort_t Ws[128*40];
  __shared__ int rrow[64];
  int m0 = blockIdx.x*64;
  int tid = threadIdx.x, wave = tid>>6, lane = tid&63;
  int lr = lane & 15, lk = (lane>>4)*8;
  if (tid < 64){
    int m = m0 + tid;
    int pt = (m<L) ? pack_t[m] : 0;
    int pb = (m<L) ? pack_b[m] : 0;
    rrow[tid] = pt*NBATCH + pb;
  }
  f32x4 acc[4][2] = {};
  for (int k0=0;k0<NCH;k0+=32){
    __syncthreads();
    {
      int r = tid>>2, kb = tid&3;
      *(bf16x8*)&Xs[r*40 + kb*8] = *(const bf16x8*)(hsbf + (size_t)rrow[r]*NCH + k0 + kb*8);
    }
    #pragma unroll
    for (int i=0;i<2;i++){
      int c = tid + i*256, r = c>>2, kb = c&3;
      *(bf16x8*)&Ws[r*40 + kb*8] = *(const bf16x8*)(Wbf + (size_t)r*NCH + k0 + kb*8);
    }
    __syncthreads();
    bf16x8 af[4], bg[2];
    #pragma unroll
    for (int m=0;m<4;m++) af[m] = *(const bf16x8*)&Xs[(m*16 + lr)*40 + lk];
    #pragma unroll
    for (int n=0;n<2;n++) bg[n] = *(const bf16x8*)&Ws[(wave*32 + n*16 + lr)*40 + lk];
    #pragma unroll
    for (int m=0;m<4;m++)
      #pragma unroll
      for (int n=0;n<2;n++)
        acc[m][n] = __builtin_amdgcn_mfma_f32_16x16x32_bf16(af[m], bg[n], acc[m][n], 0, 0, 0);
  }
  #pragma unroll
  for (int m=0;m<4;m++)
    #pragma unroll
    for (int n=0;n<2;n++)
      #pragma unroll
      for (int j=0;j<4;j++){
        int row = m0 + m*16 + (lane>>4)*4 + j;
        int col = wave*32 + n*16 + lr;
        if (row < L) out[(size_t)row*NCLS + col] = acc[m][n][j] + bias[col];
      }
}

extern "C" void kernel_launch(void* const* d_in, const int* in_sizes, int n_in,
                              void* d_out, int out_size, void* d_ws, size_t ws_size,
                              hipStream_t stream) {
  const float* feature = (const float*)d_in[0];
  const float* A       = (const float*)d_in[1];
  const int*   text    = (const int*)d_in[2];
  const int*   pack_b  = (const int*)d_in[4];
  const int*   pack_t  = (const int*)d_in[5];
  const float* emb     = (const float*)d_in[6];
  const float* Wih_f   = (const float*)d_in[7];
  const float* Whh_f   = (const float*)d_in[8];
  const float* bih_f   = (const float*)d_in[9];
  const float* bhh_f   = (const float*)d_in[10];
  const float* Wih_b   = (const float*)d_in[11];
  const float* Whh_b   = (const float*)d_in[12];
  const float* bih_b   = (const float*)d_in[13];
  const float* bhh_b   = (const float*)d_in[14];
  const float* Wih_g   = (const float*)d_in[15];
  const float* Whh_g   = (const float*)d_in[16];
  const float* bih_g   = (const float*)d_in[17];
  const float* bhh_g   = (const float*)d_in[18];
  const float* Wgen    = (const float*)d_in[19];
  const float* bgen    = (const float*)d_in[20];
  int L = in_sizes[4];

  char* ws = (char*)d_ws;
  const size_t MB = 1u<<20;
  float*    S       = (float*)(ws + 0);                    // 32 KB
  ushort_t* Wf_bf   = (ushort_t*)(ws + 1*MB);              // 256 KB
  ushort_t* Wb_bf   = (ushort_t*)(ws + 1*MB + 256*1024);   // 256 KB
  ushort_t* Wg_bf   = (ushort_t*)(ws + 1*MB + 512*1024);   // 768 KB
  ushort_t* Wgen_bf = (ushort_t*)(ws + 1*MB + 1280*1024);  // 64 KB
  ushort_t* Cbf     = (ushort_t*)(ws + 3*MB);              // 4 MB  [t][b][256]
  ushort_t* Clbf    = (ushort_t*)(ws + 7*MB);              // 4 MB
  ushort_t* hsbf    = (ushort_t*)(ws + 11*MB);             // 4 MB
  float*    Gf      = (float*)(ws + 16*MB);                // 16 MB (dead after k_lstm)
  float*    Gb      = (float*)(ws + 32*MB);                // 16 MB (dead after k_lstm)
  ushort_t* xsbf    = (ushort_t*)(ws + 16*MB);             // 8 MB, aliases Gf
  float*    gx      = (float*)(ws + 24*MB);                // 25.2 MB, aliases Gb+

  float* out_res   = (float*)d_out;
  float* out_attns = out_res + (size_t)L*NCLS;

  k_convw<<<512, 256, 0, stream>>>(Wih_f, Wf_bf, 512*256);
  k_convw<<<512, 256, 0, stream>>>(Wih_b, Wb_bf, 512*256);
  k_convw<<<1536, 256, 0, stream>>>(Wih_g, Wg_bf, 768*512);
  k_convw<<<128, 256, 0, stream>>>(Wgen, Wgen_bf, 128*256);
  k_rowsum<<<8192, 256, 0, stream>>>(A, S);
  k_pool_mfma<<<256, 256, 0, stream>>>(feature, A, S, Cbf);
  k_attns<<<L, 256, 0, stream>>>(A, S, pack_b, pack_t, out_attns);
  k_gemm_bf<<<dim3(4,64), 256, 0, stream>>>(Cbf, Wf_bf, bih_f, bhh_f, Gf, 512, 256);
  k_gemm_bf<<<dim3(4,64), 256, 0, stream>>>(Cbf, Wb_bf, bih_b, bhh_b, Gb, 512, 256);
  k_lstm<<<256, 512, 0, stream>>>(Gf, Gb, Whh_f, Whh_b, Clbf);
  k_xs<<<2048, 256, 0, stream>>>(Clbf, emb, text, xsbf);
  k_gemm_bf<<<dim3(6,64), 256, 0, stream>>>(xsbf, Wg_bf, bih_g, nullptr, gx, 768, 512);
  k_gru<<<128, 512, 0, stream>>>(gx, Whh_g, bhh_g, hsbf);
  k_logits_mfma<<<(L+63)/64, 256, 0, stream>>>(hsbf, pack_t, pack_b, Wgen_bf, bgen, out_res, L);
}